// Round 4
// baseline (606.494 us; speedup 1.0000x reference)
//
#include <hip/hip_runtime.h>

// Soft-circuit FP32 scale-by-2^k, reduced to integer bit ops.
// Row layout (element e <-> bit e of packed word):
//   bit 0      = sign
//   bits 1..8  = exponent, element 1 = MSB
//   bits 9..31 = mantissa, element 9 = MSB
//
// v4: v3's per-element pipeline (8 lanes/row, low-quad DPP gather, ballot
// k==0 test) wrapped in a grid-stride loop with a 4-row batch per iteration:
//  - 8 independent global loads in flight per wave (4x deeper MLP than the
//    one-shot v1/v3 structure)
//  - kernarg + address setup amortized over ~32 float4s per thread
//  - plain stores (v2 measured: nontemporal stores +12% WRITE_SIZE)
// Memory-bound: 804 MB logical traffic.

__device__ __forceinline__ unsigned rev8(unsigned v) {
    // reverse the low 8 bits
    return __builtin_bitreverse32(v) >> 24;
}

__device__ __forceinline__ unsigned nib4(const float4 v) {
    return (unsigned)(v.x != 0.0f)
         | ((unsigned)(v.y != 0.0f) << 1)
         | ((unsigned)(v.z != 0.0f) << 2)
         | ((unsigned)(v.w != 0.0f) << 3);
}

// OR across the 4 lanes of a quad using DPP quad_perm (VALU pipe only).
__device__ __forceinline__ unsigned quad_or(unsigned w) {
    // quad_perm [1,0,3,2] = 0xB1  (lane ^ 1)
    w |= (unsigned)__builtin_amdgcn_update_dpp(0, (int)w, 0xB1, 0xF, 0xF, true);
    // quad_perm [2,3,0,1] = 0x4E  (lane ^ 2)
    w |= (unsigned)__builtin_amdgcn_update_dpp(0, (int)w, 0x4E, 0xF, 0xF, true);
    return w;
}

// identical arithmetic to the harness-verified v3
__device__ __forceinline__ float4 process(const float4 vx, const float4 vk,
                                          unsigned g, unsigned sh,
                                          unsigned kmask, unsigned me,
                                          unsigned lane) {
    unsigned nibx = nib4(vx);
    unsigned nibk = nib4(vk);

    // k == 0 test (ignoring k's sign bit): one ballot over the 8-lane group
    unsigned long long ball = __ballot((nibk & kmask) != 0u);
    bool kz = (((unsigned)(ball >> (lane & 56u)) & 0xFFu) == 0u);

    // gather row bits 0..15 of x and k across the low quad
    unsigned w = quad_or((nibx << ((g & 3u) * 4u))
                       | (nibk << (16u + (g & 3u) * 4u)));
    unsigned xlo = w & 0xFFFFu;
    unsigned klo = w >> 16;

    unsigned ek   = rev8((klo >> 1) & 0xFFu);                                  // exponent of k
    unsigned val  = 0x80u | (__builtin_bitreverse32((klo >> 9) & 0x7Fu) >> 25);// 1.m (8-bit)
    unsigned s    = (ek - 127u) & 7u;
    unsigned kabs = val >> (7u - s);
    unsigned kfin = (klo & 1u) ? ((0u - kabs) & 0xFFu) : kabs;
    unsigned ex   = rev8((xlo >> 1) & 0xFFu);
    unsigned er   = rev8((ex + kfin) & 0xFFu) << 1;   // new exponent, bits 1..8

    unsigned scaled_n = ((er >> sh) & me) | (nibx & (me ^ 0xFu));
    unsigned res      = kz ? nibx : scaled_n;

    float4 out;
    out.x = (float)(res & 1u);
    out.y = (float)((res >> 1) & 1u);
    out.z = (float)((res >> 2) & 1u);
    out.w = (float)((res >> 3) & 1u);
    return out;
}

__global__ __launch_bounds__(256) void spike_scale_kernel(
        const float4* __restrict__ x4,
        const float4* __restrict__ k4,
        float4* __restrict__ o4,
        int nvec) {
    const int T   = (int)(gridDim.x * 256u);
    int tid       = (int)(blockIdx.x * 256u + threadIdx.x);

    const unsigned g     = (unsigned)(tid & 7);       // position within the row
    const unsigned sh    = g * 4u;
    const unsigned kmask = (g == 0u) ? 0xEu : 0xFu;   // drop k sign bit in lane 0
    const unsigned me    = (0x1FEu >> sh) & 0xFu;     // my exponent-bit mask
    const unsigned lane  = (unsigned)(threadIdx.x & 63u);

    int i = tid;
    // main loop: 4 rows-worth per iteration, 8 loads in flight
    for (; i + 3 * T < nvec; i += 4 * T) {
        float4 a0 = x4[i];
        float4 a1 = x4[i + T];
        float4 a2 = x4[i + 2 * T];
        float4 a3 = x4[i + 3 * T];
        float4 b0 = k4[i];
        float4 b1 = k4[i + T];
        float4 b2 = k4[i + 2 * T];
        float4 b3 = k4[i + 3 * T];

        float4 r0 = process(a0, b0, g, sh, kmask, me, lane);
        float4 r1 = process(a1, b1, g, sh, kmask, me, lane);
        float4 r2 = process(a2, b2, g, sh, kmask, me, lane);
        float4 r3 = process(a3, b3, g, sh, kmask, me, lane);

        o4[i]         = r0;
        o4[i + T]     = r1;
        o4[i + 2 * T] = r2;
        o4[i + 3 * T] = r3;
    }
    // tail (8-lane row groups stay converged: nvec is a multiple of 8)
    for (; i < nvec; i += T) {
        o4[i] = process(x4[i], k4[i], g, sh, kmask, me, lane);
    }
}

extern "C" void kernel_launch(void* const* d_in, const int* in_sizes, int n_in,
                              void* d_out, int out_size, void* d_ws, size_t ws_size,
                              hipStream_t stream) {
    const float4* x4 = (const float4*)d_in[0];
    const float4* k4 = (const float4*)d_in[1];
    float4* o4 = (float4*)d_out;

    int n_elems = in_sizes[0];          // N * 32 floats
    int nvec    = n_elems / 4;          // float4 vectors
    int blocks  = (nvec + 255) / 256;
    if (blocks > 2048) blocks = 2048;   // grid-stride; ~8 blocks/CU

    spike_scale_kernel<<<blocks, 256, 0, stream>>>(x4, k4, o4, nvec);
}

// Round 5
// 577.072 us; speedup vs baseline: 1.0510x; 1.0510x over previous
//
#include <hip/hip_runtime.h>

// Soft-circuit FP32 scale-by-2^k, reduced to integer bit ops.
// Row layout (element e <-> bit e of packed word):
//   bit 0      = sign
//   bits 1..8  = exponent, element 1 = MSB
//   bits 9..31 = mantissa, element 9 = MSB
//
// v5: v3's verified per-element pipeline, one-shot (no loop), but each
// thread handles FOUR float4s spaced 256 apart inside a block-contiguous
// 1024-float4 (16 KB) chunk:
//  - 8 independent global loads in flight per wave (4x bytes/wave vs v3:
//    3 KB -> 12 KB), amortizing the latency-dominated wave lifetime
//  - all accesses stay 1 KB-contiguous per instruction and within a 16 KB
//    window per array (no v4-style 8 MB striding, no persistent-loop convoy)
//  - plain stores (v2 measured: nontemporal stores +12% WRITE_SIZE)
// Memory-bound: 804 MB logical traffic; HBM-compulsory 536 MB.

__device__ __forceinline__ unsigned rev8(unsigned v) {
    // reverse the low 8 bits
    return __builtin_bitreverse32(v) >> 24;
}

__device__ __forceinline__ unsigned nib4(const float4 v) {
    return (unsigned)(v.x != 0.0f)
         | ((unsigned)(v.y != 0.0f) << 1)
         | ((unsigned)(v.z != 0.0f) << 2)
         | ((unsigned)(v.w != 0.0f) << 3);
}

// OR across the 4 lanes of a quad using DPP quad_perm (VALU pipe only).
__device__ __forceinline__ unsigned quad_or(unsigned w) {
    // quad_perm [1,0,3,2] = 0xB1  (lane ^ 1)
    w |= (unsigned)__builtin_amdgcn_update_dpp(0, (int)w, 0xB1, 0xF, 0xF, true);
    // quad_perm [2,3,0,1] = 0x4E  (lane ^ 2)
    w |= (unsigned)__builtin_amdgcn_update_dpp(0, (int)w, 0x4E, 0xF, 0xF, true);
    return w;
}

// identical arithmetic to the harness-verified v3
__device__ __forceinline__ float4 process(const float4 vx, const float4 vk,
                                          unsigned g, unsigned sh,
                                          unsigned kmask, unsigned me,
                                          unsigned lane) {
    unsigned nibx = nib4(vx);
    unsigned nibk = nib4(vk);

    // k == 0 test (ignoring k's sign bit): one ballot over the 8-lane group
    unsigned long long ball = __ballot((nibk & kmask) != 0u);
    bool kz = (((unsigned)(ball >> (lane & 56u)) & 0xFFu) == 0u);

    // gather row bits 0..15 of x and k across the low quad
    unsigned w = quad_or((nibx << ((g & 3u) * 4u))
                       | (nibk << (16u + (g & 3u) * 4u)));
    unsigned xlo = w & 0xFFFFu;
    unsigned klo = w >> 16;

    unsigned ek   = rev8((klo >> 1) & 0xFFu);                                  // exponent of k
    unsigned val  = 0x80u | (__builtin_bitreverse32((klo >> 9) & 0x7Fu) >> 25);// 1.m (8-bit)
    unsigned s    = (ek - 127u) & 7u;
    unsigned kabs = val >> (7u - s);
    unsigned kfin = (klo & 1u) ? ((0u - kabs) & 0xFFu) : kabs;
    unsigned ex   = rev8((xlo >> 1) & 0xFFu);
    unsigned er   = rev8((ex + kfin) & 0xFFu) << 1;   // new exponent, bits 1..8

    unsigned scaled_n = ((er >> sh) & me) | (nibx & (me ^ 0xFu));
    unsigned res      = kz ? nibx : scaled_n;

    float4 out;
    out.x = (float)(res & 1u);
    out.y = (float)((res >> 1) & 1u);
    out.z = (float)((res >> 2) & 1u);
    out.w = (float)((res >> 3) & 1u);
    return out;
}

__global__ __launch_bounds__(256) void spike_scale_kernel(
        const float4* __restrict__ x4,
        const float4* __restrict__ k4,
        float4* __restrict__ o4,
        int nvec) {
    const int t    = (int)threadIdx.x;
    const int base = (int)blockIdx.x * 1024 + t;

    // all 4 of this thread's indices are congruent mod 8 -> same g/lane setup
    const unsigned g     = (unsigned)(base & 7);
    const unsigned sh    = g * 4u;
    const unsigned kmask = (g == 0u) ? 0xEu : 0xFu;   // drop k sign bit in lane 0
    const unsigned me    = (0x1FEu >> sh) & 0xFu;     // my exponent-bit mask
    const unsigned lane  = (unsigned)(threadIdx.x & 63u);

    if (base + 768 < nvec) {
        // full-chunk fast path: 8 unconditional loads up front
        float4 a0 = x4[base];
        float4 a1 = x4[base + 256];
        float4 a2 = x4[base + 512];
        float4 a3 = x4[base + 768];
        float4 b0 = k4[base];
        float4 b1 = k4[base + 256];
        float4 b2 = k4[base + 512];
        float4 b3 = k4[base + 768];

        o4[base]       = process(a0, b0, g, sh, kmask, me, lane);
        o4[base + 256] = process(a1, b1, g, sh, kmask, me, lane);
        o4[base + 512] = process(a2, b2, g, sh, kmask, me, lane);
        o4[base + 768] = process(a3, b3, g, sh, kmask, me, lane);
    } else {
        // tail block: guarded per element (row groups of 8 stay intact since
        // the guard granularity within a wave follows base, and nvec % 8 == 0)
        #pragma unroll
        for (int j = 0; j < 4; ++j) {
            int i = base + j * 256;
            if (i < nvec) {
                o4[i] = process(x4[i], k4[i], g, sh, kmask, me, lane);
            }
        }
    }
}

extern "C" void kernel_launch(void* const* d_in, const int* in_sizes, int n_in,
                              void* d_out, int out_size, void* d_ws, size_t ws_size,
                              hipStream_t stream) {
    const float4* x4 = (const float4*)d_in[0];
    const float4* k4 = (const float4*)d_in[1];
    float4* o4 = (float4*)d_out;

    int n_elems = in_sizes[0];          // N * 32 floats
    int nvec    = n_elems / 4;          // float4 vectors
    int blocks  = (nvec + 1023) / 1024; // 1024 float4s (16 KB) per block

    spike_scale_kernel<<<blocks, 256, 0, stream>>>(x4, k4, o4, nvec);
}

// Round 6
// 557.506 us; speedup vs baseline: 1.0879x; 1.0351x over previous
//
#include <hip/hip_runtime.h>

// Soft-circuit FP32 scale-by-2^k, reduced to integer bit ops.
// Row layout (element e <-> bit e of packed word):
//   bit 0      = sign
//   bits 1..8  = exponent, element 1 = MSB
//   bits 9..31 = mantissa, element 9 = MSB
//
// v6: v3's exact structure (one-shot, 1 float4/thread, 8 lanes/row, DPP
// low-quad gather, ballot k==0 test -- the measured 173 us local optimum),
// with ONE variable changed: input loads are NONTEMPORAL (nt / evict-first).
// Theory: the 804 MB/dispatch streamed through the thrashing 256 MB L3 is
// what throttles HBM to 3.1 TB/s (copy achieves 6.29 TB/s at the same 1R:1W
// HBM mix); inputs have no intra-dispatch reuse, so bypassing L3 retention
// trades the 50% cross-dispatch hit rate for clean streaming.
// Stores stay plain (v2: nt stores on scattered 64B cost +12% WRITE_SIZE).

// native vector type for __builtin_nontemporal_load (HIP_vector_type rejected)
typedef float fvec4 __attribute__((ext_vector_type(4)));

__device__ __forceinline__ unsigned rev8(unsigned v) {
    // reverse the low 8 bits
    return __builtin_bitreverse32(v) >> 24;
}

__device__ __forceinline__ unsigned nib4(const fvec4 v) {
    return (unsigned)(v.x != 0.0f)
         | ((unsigned)(v.y != 0.0f) << 1)
         | ((unsigned)(v.z != 0.0f) << 2)
         | ((unsigned)(v.w != 0.0f) << 3);
}

// OR across the 4 lanes of a quad using DPP quad_perm (VALU pipe only).
__device__ __forceinline__ unsigned quad_or(unsigned w) {
    // quad_perm [1,0,3,2] = 0xB1  (lane ^ 1)
    w |= (unsigned)__builtin_amdgcn_update_dpp(0, (int)w, 0xB1, 0xF, 0xF, true);
    // quad_perm [2,3,0,1] = 0x4E  (lane ^ 2)
    w |= (unsigned)__builtin_amdgcn_update_dpp(0, (int)w, 0x4E, 0xF, 0xF, true);
    return w;
}

__global__ __launch_bounds__(256) void spike_scale_kernel(
        const float4* __restrict__ x4,
        const float4* __restrict__ k4,
        float4* __restrict__ o4,
        int nvec) {
    int idx = blockIdx.x * 256 + threadIdx.x;
    if (idx >= nvec) return;

    const fvec4* xv = (const fvec4*)x4;
    const fvec4* kv = (const fvec4*)k4;
    fvec4 vx = __builtin_nontemporal_load(&xv[idx]);
    fvec4 vk = __builtin_nontemporal_load(&kv[idx]);

    unsigned g  = (unsigned)(idx & 7);   // this thread's 4 elems within the row
    unsigned sh = g * 4u;

    unsigned nibx = nib4(vx);
    unsigned nibk = nib4(vk);

    // ---- k == 0 test (ignoring k's sign bit): one ballot, no chain ----
    unsigned kmask = (g == 0u) ? 0xEu : 0xFu;       // drop sign bit in lane 0
    unsigned long long ball = __ballot((nibk & kmask) != 0u);
    unsigned lane = (unsigned)(threadIdx.x & 63u);
    bool kz = (((unsigned)(ball >> (lane & 56u)) & 0xFFu) == 0u);

    // ---- gather row bits 0..15 of x and k across the low quad ----
    // lanes g>=4 compute garbage here, but they never use it (me == 0 below)
    unsigned w = quad_or((nibx << ((g & 3u) * 4u))
                       | (nibk << (16u + (g & 3u) * 4u)));
    unsigned xlo = w & 0xFFFFu;     // x bits 0..15 (sign + exponent + m0..m6)
    unsigned klo = w >> 16;         // k bits 0..15

    // ---- identical arithmetic to the harness-verified v1/v3 ----
    unsigned ek   = rev8((klo >> 1) & 0xFFu);                                  // exponent of k
    unsigned val  = 0x80u | (__builtin_bitreverse32((klo >> 9) & 0x7Fu) >> 25);// 1.m (8-bit)
    unsigned s    = (ek - 127u) & 7u;
    unsigned kabs = val >> (7u - s);
    unsigned kfin = (klo & 1u) ? ((0u - kabs) & 0xFFu) : kabs;
    unsigned ex   = rev8((xlo >> 1) & 0xFFu);
    unsigned er   = rev8((ex + kfin) & 0xFFu) << 1;   // new exponent, bits 1..8

    // per-lane recombine: which of my 4 bits are exponent bits?
    unsigned me       = (0x1FEu >> sh) & 0xFu;        // 0xE, 0xF, 0x1, 0, 0, ...
    unsigned scaled_n = ((er >> sh) & me) | (nibx & (me ^ 0xFu));
    unsigned res      = kz ? nibx : scaled_n;

    float4 out;
    out.x = (float)(res & 1u);
    out.y = (float)((res >> 1) & 1u);
    out.z = (float)((res >> 2) & 1u);
    out.w = (float)((res >> 3) & 1u);
    o4[idx] = out;
}

extern "C" void kernel_launch(void* const* d_in, const int* in_sizes, int n_in,
                              void* d_out, int out_size, void* d_ws, size_t ws_size,
                              hipStream_t stream) {
    const float4* x4 = (const float4*)d_in[0];
    const float4* k4 = (const float4*)d_in[1];
    float4* o4 = (float4*)d_out;

    int n_elems = in_sizes[0];          // N * 32 floats
    int nvec    = n_elems / 4;          // float4 vectors
    int blocks  = (nvec + 255) / 256;

    spike_scale_kernel<<<blocks, 256, 0, stream>>>(x4, k4, o4, nvec);
}